// Round 7
// baseline (287.245 us; speedup 1.0000x reference)
//
#include <hip/hip_runtime.h>
#include <hip/hip_bf16.h>

#define RD 64
#define UD 64
#define VD 64
#define HD 128
#define XD 64
#define NB 8
#define SITES 1024

typedef float f32x4 __attribute__((ext_vector_type(4)));
typedef __bf16 bf16x4 __attribute__((ext_vector_type(4)));
typedef __bf16 bf16x8 __attribute__((ext_vector_type(8)));
typedef unsigned int u32x4 __attribute__((ext_vector_type(4)));
typedef unsigned short u16;

// ---------------- kprep: all three input transforms in one launch ----------------
// b < 256   : w2 [x][r][h] fp32 -> w2t bf16 [r][x][h]
// b < 384   : r  [n][s][r] fp32 -> rt fp32 [n][r][s]
// else      : u  [n][r][u][v] fp32 -> ut fp32 [r][u][v][n]   (2048 blocks)
__global__ void kprep(const float* __restrict__ w2, u16* __restrict__ w2t,
                      const float* __restrict__ r, float* __restrict__ rt,
                      const float* __restrict__ u, float* __restrict__ ut) {
  __shared__ float tl[64][68];
  int b = blockIdx.x;
  int t = threadIdx.x;
  if (b < 256) {
    int rr = b >> 2, qq = b & 3;
    for (int i = 0; i < 8; ++i) {
      int idx = qq * 2048 + i * 256 + t;   // (x,h)
      int x = idx >> 7, h = idx & 127;
      float val = w2[((size_t)x * RD + rr) * HD + h];
      __hip_bfloat16 hv = __float2bfloat16(val);
      w2t[((size_t)rr * XD + x) * HD + h] = *(u16*)&hv;
    }
  } else if (b < 384) {
    int bb = b - 256;
    int n = bb >> 4, sb = (bb & 15) * 64;
    for (int i = 0; i < 4; ++i) {
      int flat = i * 256 + t;
      int s = flat >> 4, ch = flat & 15;
      f32x4 d = *(const f32x4*)(r + ((size_t)(n * SITES + sb + s) * RD + ch * 4));
      *(f32x4*)&tl[s][ch * 4] = d;
    }
    __syncthreads();
    for (int i = 0; i < 4; ++i) {
      int flat = i * 256 + t;
      int rr = flat >> 4, ch = flat & 15;
      f32x4 o;
      o.x = tl[ch * 4 + 0][rr];
      o.y = tl[ch * 4 + 1][rr];
      o.z = tl[ch * 4 + 2][rr];
      o.w = tl[ch * 4 + 3][rr];
      *(f32x4*)(rt + ((size_t)(n * RD + rr) * SITES + sb + ch * 4)) = o;
    }
  } else {
    int f = (b - 384) * 256 + t;        // 524288 f32x4 units of ut
    int nh = f & 1, v = (f >> 1) & 63, uu = (f >> 7) & 63, rr = f >> 13;
    f32x4 o;
#pragma unroll
    for (int k = 0; k < 4; ++k)
      o[k] = u[(((size_t)(nh * 4 + k) * RD + rr) * UD + uu) * VD + v];
    *(f32x4*)(ut + (size_t)f * 4) = o;
  }
}

// ---------------- k_a: a[n,r,h,v] bf16 = sum_u w1[r,u,v,h]*u[n,r,u,v] ----------------
// R6 lesson kept: simple unroll-4 body (no manual ring), TLP from grid.
// R7: parallelism via h-split8 (not u-split) -> w1 still read ONCE, no fp32
// partials, no k_a_red launch.  1024 blocks = 4 blocks/CU = 16 waves/CU.
__global__ __launch_bounds__(256, 4) void k_a(const float* __restrict__ w1,
                                              const float* __restrict__ ut,
                                              u16* __restrict__ at) {
  __shared__ u16 tile[16][36];        // h-local x v-local (+4 pad)
  int b = blockIdx.x;                 // 1024 = rr(64) x vh(2) x hb(8)
  int rr = b >> 4, vh = (b >> 3) & 1, hb = b & 7;
  int t = threadIdx.x;
  int vl = t >> 3, hs = t & 7;        // v-local (32), h-strip (2 h each)
  int v = vh * 32 + vl;
  int h0 = hb * 16 + hs * 2;
  const float* w1p = w1 + ((size_t)(rr * UD) * VD + v) * HD + h0;   // +8192 fl per uu
  const float* up  = ut + ((size_t)(rr * UD) * VD + v) * NB;        // +512 fl per uu

  float acc[8][2];
#pragma unroll
  for (int n = 0; n < 8; ++n) { acc[n][0] = 0.f; acc[n][1] = 0.f; }

#pragma unroll 4
  for (int uu = 0; uu < 64; ++uu) {
    float2 wv = *(const float2*)(w1p + (size_t)uu * (VD * HD));
    f32x4 a0 = *(const f32x4*)(up + (size_t)uu * (VD * NB));
    f32x4 a1 = *(const f32x4*)(up + (size_t)uu * (VD * NB) + 4);
    float un[8];
    un[0] = a0.x; un[1] = a0.y; un[2] = a0.z; un[3] = a0.w;
    un[4] = a1.x; un[5] = a1.y; un[6] = a1.z; un[7] = a1.w;
#pragma unroll
    for (int n = 0; n < 8; ++n) {
      acc[n][0] += un[n] * wv.x;
      acc[n][1] += un[n] * wv.y;
    }
  }

  // epilogue: LDS transpose per n -> 4 B/lane stores over full 64 B v-runs
  int hl = t >> 4, vs = t & 15;
  for (int n = 0; n < 8; ++n) {
    __syncthreads();
#pragma unroll
    for (int j = 0; j < 2; ++j) {
      __hip_bfloat16 hv = __float2bfloat16(acc[n][j]);
      tile[hs * 2 + j][vl] = *(u16*)&hv;
    }
    __syncthreads();
    unsigned int blk = *(const unsigned int*)&tile[hl][vs * 2];
    *(unsigned int*)(at + ((size_t)(n * RD + rr) * HD + hb * 16 + hl) * VD +
                     vh * 32 + vs * 2) = blk;
  }
}

// ---------------- k_main: fused GEMM1 (P^T = A_r^T * V^T) + relu*r + GEMM2 ----------------
// R7: s-tile 64 (grid 1024 = n8 x st16 x rc8), smaller per-wave tiles
// (cc[2][4], o[2][2], est ~155 VGPR), LDS 32 KB -> 3 blocks/CU (was 2).
// Single barrier per rr via double-buffered swizzled P.
__global__ __launch_bounds__(256, 3) void k_main(const float* __restrict__ vin,
                                                 const u16* __restrict__ at,
                                                 const u16* __restrict__ w2t,
                                                 const float* __restrict__ rt,
                                                 float* __restrict__ pbuf) {
  __shared__ __align__(16) char Plds[2 * 64 * 256];   // 32 KB
  int b = blockIdx.x;                 // 1024 = n(8) x st(16) x rc(8)
  int rc = b & 7, st = (b >> 3) & 15, n = b >> 7;
  int t = threadIdx.x;
  int w = t >> 6, L = t & 63, q = L >> 4, c = L & 15;
  int g2m = w >> 1, g2x = w & 1;      // GEMM2: s-half x x-half

  // V fragments (B-operand of GEMM1): all 4 waves load the full 64-s tile
  bf16x8 vf[4][2];
#pragma unroll
  for (int nt = 0; nt < 4; ++nt)
#pragma unroll
    for (int ks = 0; ks < 2; ++ks) {
      int s = nt * 16 + c;
      const float* vp = vin + ((size_t)(n * SITES + st * 64 + s) * VD + ks * 32 + q * 8);
      f32x4 a0 = *(const f32x4*)vp;
      f32x4 a1 = *(const f32x4*)(vp + 4);
      bf16x8 f;
      f[0] = (__bf16)a0.x; f[1] = (__bf16)a0.y; f[2] = (__bf16)a0.z; f[3] = (__bf16)a0.w;
      f[4] = (__bf16)a1.x; f[5] = (__bf16)a1.y; f[6] = (__bf16)a1.z; f[7] = (__bf16)a1.w;
      vf[nt][ks] = f;
    }

  f32x4 o[2][2];
#pragma unroll
  for (int i = 0; i < 2; i++)
#pragma unroll
    for (int j = 0; j < 2; j++) o[i][j] = (f32x4)0.f;

  for (int rr = rc * 8; rr < rc * 8 + 8; ++rr) {
    const u16* abase = at + (size_t)(n * RD + rr) * 8192;   // [h][v] plain

    // A-frags direct from global (wave's h-quarter = w*32)
    bf16x8 af[2][2];
#pragma unroll
    for (int mt = 0; mt < 2; ++mt)
#pragma unroll
      for (int ks = 0; ks < 2; ++ks) {
        int h = w * 32 + mt * 16 + c;
        int vb = ks * 4 + q;
        af[mt][ks] = *(const bf16x8*)(abase + (size_t)h * VD + vb * 8);
      }
    // W2r b-frags from global (L2-hot); wave's x-half = g2x*32
    u32x4 wraw[2][4];
#pragma unroll
    for (int nt = 0; nt < 2; ++nt)
#pragma unroll
      for (int k2 = 0; k2 < 4; ++k2) {
        int xg = g2x * 32 + nt * 16 + c;
        wraw[nt][k2] = *(const u32x4*)((const char*)w2t +
                        (((size_t)(rr * XD + xg)) * HD + k2 * 32 + q * 8) * 2);
      }
    float rsc[4];
#pragma unroll
    for (int nt = 0; nt < 4; ++nt)
      rsc[nt] = rt[(size_t)(n * RD + rr) * SITES + st * 64 + nt * 16 + c];

    // GEMM1: D = A_r^T (m=h, wave quarter) x V^T (n=s 64), K=v=64
    f32x4 cc[2][4];
#pragma unroll
    for (int mt = 0; mt < 2; ++mt)
#pragma unroll
      for (int nt = 0; nt < 4; ++nt) cc[mt][nt] = (f32x4)0.f;
#pragma unroll
    for (int ks = 0; ks < 2; ++ks)
#pragma unroll
      for (int mt = 0; mt < 2; ++mt)
#pragma unroll
        for (int nt = 0; nt < 4; ++nt)
          cc[mt][nt] = __builtin_amdgcn_mfma_f32_16x16x32_bf16(af[mt][ks], vf[nt][ks],
                                                               cc[mt][nt], 0, 0, 0);

    // relu, scale by r, pack to Plds buf rr&1, XOR-swizzled 16B blocks:
    // row s (256 B), h-block blk=h>>3 stored at (blk ^ (s&15)).
    char* PB = Plds + (rr & 1) * 16384;
#pragma unroll
    for (int mt = 0; mt < 2; ++mt)
#pragma unroll
      for (int nt = 0; nt < 4; ++nt) {
        float sc = rsc[nt];
        bf16x4 pv;
#pragma unroll
        for (int jj = 0; jj < 4; ++jj) {
          float x = cc[mt][nt][jj];
          x = x > 0.f ? x : 0.f;
          pv[jj] = (__bf16)(x * sc);
        }
        int s = nt * 16 + c;                     // s&15 == c
        int blk = w * 4 + mt * 2 + (q >> 1);     // = h>>3
        *(bf16x4*)(PB + (size_t)s * 256 + (size_t)((blk ^ c) * 16 + (q & 1) * 8)) = pv;
      }
    __syncthreads();   // single barrier per rr (writers done before readers; see R4)

    // GEMM2: O[s,x] += P (m=s, A-op) x W2r^T (n=x), K=h=128
#pragma unroll
    for (int k2 = 0; k2 < 4; ++k2) {
      bf16x8 wf0 = __builtin_bit_cast(bf16x8, wraw[0][k2]);
      bf16x8 wf1 = __builtin_bit_cast(bf16x8, wraw[1][k2]);
#pragma unroll
      for (int mt = 0; mt < 2; ++mt) {
        int s = g2m * 32 + mt * 16 + c;          // s&15 == c
        int blk = k2 * 4 + q;                    // = h>>3
        bf16x8 pf = *(const bf16x8*)(PB + (size_t)s * 256 + (size_t)((blk ^ c) * 16));
        o[mt][0] = __builtin_amdgcn_mfma_f32_16x16x32_bf16(pf, wf0, o[mt][0], 0, 0, 0);
        o[mt][1] = __builtin_amdgcn_mfma_f32_16x16x32_bf16(pf, wf1, o[mt][1], 0, 0, 0);
      }
    }
  }
  // epilogue: plain vector stores to pbuf[rc][n][st][x][s64]
#pragma unroll
  for (int mt = 0; mt < 2; ++mt)
#pragma unroll
    for (int nt = 0; nt < 2; ++nt) {
      int s0 = g2m * 32 + mt * 16 + q * 4;
      int x = g2x * 32 + nt * 16 + c;
      size_t off = ((((size_t)rc * NB + n) * 16 + st) * XD + x) * 64 + s0;
      *(f32x4*)(pbuf + off) = o[mt][nt];
    }
}

// ---------------- k_reduce: out[n][s][x] = sum_rc pbuf[rc][n][st][x][s64] ----------------
__global__ __launch_bounds__(256) void k_reduce(const float* __restrict__ pbuf,
                                                float* __restrict__ out) {
  __shared__ float tile[64][68];
  int b = blockIdx.x;                 // 128 = n(8) x st(16)
  int n = b >> 4, st = b & 15;
  int t = threadIdx.x;
  int sq = t & 15, xl = t >> 4;       // phase-1: s-quad (16), x-lane (16)
#pragma unroll
  for (int p = 0; p < 4; ++p) {
    int x = p * 16 + xl;
    f32x4 sum = (f32x4)0.f;
#pragma unroll
    for (int rcc = 0; rcc < 8; ++rcc) {
      size_t off = ((((size_t)rcc * NB + n) * 16 + st) * XD + x) * 64 + sq * 4;
      f32x4 d = *(const f32x4*)(pbuf + off);
      sum.x += d.x; sum.y += d.y; sum.z += d.z; sum.w += d.w;
    }
#pragma unroll
    for (int k = 0; k < 4; ++k) tile[sq * 4 + k][x] = sum[k];
  }
  __syncthreads();
  // phase-2: coalesced out write, f32x4 along x
#pragma unroll
  for (int k = 0; k < 4; ++k) {
    int flat = k * 256 + t;
    int s = flat >> 4, c4 = flat & 15;
    f32x4 o;
#pragma unroll
    for (int j = 0; j < 4; ++j) o[j] = tile[s][c4 * 4 + j];
    *(f32x4*)(out + ((size_t)(n * SITES + st * 64 + s) * XD + c4 * 4)) = o;
  }
}

extern "C" void kernel_launch(void* const* d_in, const int* in_sizes, int n_in,
                              void* d_out, int out_size, void* d_ws, size_t ws_size,
                              hipStream_t stream) {
  const float* r  = (const float*)d_in[0];
  const float* u  = (const float*)d_in[1];
  const float* v  = (const float*)d_in[2];
  const float* w1 = (const float*)d_in[3];
  const float* w2 = (const float*)d_in[4];
  float* out = (float*)d_out;
  char* ws = (char*)d_ws;
  u16* at     = (u16*)(ws);                         // 8 MB  bf16 a, [n][r][h][v]
  u16* w2t    = (u16*)(ws + ((size_t)8 << 20));     // 1 MB  bf16 w2 [r][x][h]
  float* rt   = (float*)(ws + ((size_t)9 << 20));   // 2 MB  fp32 r [n][r][s]
  float* ut   = (float*)(ws + ((size_t)11 << 20));  // 8 MB  fp32 u [r][u][v][n]
  float* pbuf = (float*)(ws + ((size_t)19 << 20));  // 16 MB fp32 out-partials [rc][n][st][x][s64]

  hipLaunchKernelGGL(kprep, dim3(2432), dim3(256), 0, stream, w2, w2t, r, rt, u, ut);
  hipLaunchKernelGGL(k_a, dim3(1024), dim3(256), 0, stream, w1, ut, at);
  hipLaunchKernelGGL(k_main, dim3(1024), dim3(256), 0, stream, v, at, w2t, rt, pbuf);
  hipLaunchKernelGGL(k_reduce, dim3(128), dim3(256), 0, stream, pbuf, out);
}